// Round 7
// baseline (61.361 us; speedup 1.0000x reference)
//
#include <hip/hip_runtime.h>
#include <math.h>

#define NN 4096
#define INDIM 45
#define HH 44
#define NHEAD 4
#define HD 11
#define NEDGE 131072
#define CAP 128            // max allowed cols per row (deg ~ Poisson(32)+diag; max row ~65)
#define MASKW (NN / 64)
#define NPB 32             // nodes per block in proj_zero

__device__ __forceinline__ float wsum64(float v) {
    #pragma unroll
    for (int i = 32; i > 0; i >>= 1) v += __shfl_xor(v, i, 64);
    return v;
}
__device__ __forceinline__ float wmax64(float v) {
    #pragma unroll
    for (int i = 32; i > 0; i >>= 1) v = fmaxf(v, __shfl_xor(v, i, 64));
    return v;
}

// ---------------- Kernel 1: zero mask + fused input/QKV projection ----------------
__global__ __launch_bounds__(256)
void proj_zero(const float* __restrict__ nf,
               const float* __restrict__ Wp, const float* __restrict__ bp,
               const float* __restrict__ Wq, const float* __restrict__ bq,
               const float* __restrict__ Wk, const float* __restrict__ bk,
               const float* __restrict__ Wv, const float* __restrict__ bv,
               unsigned long long* __restrict__ mask,
               float* __restrict__ Qs, float* __restrict__ Ks, float* __restrict__ Vs) {
    const int tid = threadIdx.x;
    const int gsz = gridDim.x * 256;
    for (int i = blockIdx.x * 256 + tid; i < NN * MASKW; i += gsz) mask[i] = 0ull;

    __shared__ float xs[NPB][HH];
    const int n0 = blockIdx.x * NPB;
    for (int idx = tid; idx < NPB * HH; idx += 256) {
        int nl = idx / HH, j = idx - nl * HH;
        const float* row = nf + (size_t)(n0 + nl) * INDIM;
        float a = bp[j];
        #pragma unroll
        for (int k = 0; k < INDIM; ++k) a += row[k] * Wp[k * HH + j];
        xs[nl][j] = a;
    }
    __syncthreads();
    for (int idx = tid; idx < NPB * HH; idx += 256) {
        int nl = idx / HH, j = idx - nl * HH;
        const float* row = xs[nl];
        float aq = bq[j], ak = bk[j], av = bv[j];
        #pragma unroll
        for (int k = 0; k < HH; ++k) {
            float xv = row[k];
            aq += xv * Wq[k * HH + j];
            ak += xv * Wk[k * HH + j];
            av += xv * Wv[k * HH + j];
        }
        size_t o = (size_t)(n0 + nl) * HH + j;
        Qs[o] = aq; Ks[o] = ak; Vs[o] = av;
    }
}

// ---------------- Kernel 2: scatter edges (diagonal handled in attn) ----------------
__global__ __launch_bounds__(256)
void build_mask(const int* __restrict__ ei, unsigned long long* __restrict__ mask) {
    int i = blockIdx.x * blockDim.x + threadIdx.x;
    if (i < NEDGE) {
        int r = ei[i];          // query
        int c = ei[NEDGE + i];  // key
        atomicOr(&mask[(size_t)r * MASKW + (c >> 6)], 1ull << (c & 63));
    }
}

// ---------------- Kernel 3: sparse attention, ONE WAVE per row (all 4 heads) ----------------
// No __syncthreads: each wave independently compacts its row's mask into its own LDS
// segment (intra-wave program order + lgkmcnt), gathers temporal once per (row,col),
// updates all 4 heads, butterfly-merges, and applies the fused @Wo+bo per-lane.
// 1024 blocks x 4 waves = 4096 waves = one row each; ~112 VGPR -> 4 waves/SIMD ->
// the whole grid is co-resident, so total time ~ one dependency chain.
__global__ __launch_bounds__(256)
void attn_fused(const float* __restrict__ Qs, const float* __restrict__ Ks,
                const float* __restrict__ Vs, const float* __restrict__ temporal,
                const unsigned long long* __restrict__ mask,
                const float* __restrict__ Wo, const float* __restrict__ bo,
                float* __restrict__ out) {
    const int tid = threadIdx.x;
    const int lane = tid & 63;
    const int wv = tid >> 6;
    const int n = blockIdx.x * 4 + wv;
    const float scale = 0.30151134457776363f;  // 1/sqrt(11)
    const float tbmul = 9.99990000099999f;     // 1/(0.1+1e-6)

    __shared__ float qs_s[4][HH];
    __shared__ int cols_s[4][CAP];

    // stage query row (independent of mask; overlaps the mask load)
    if (lane < HH) qs_s[wv][lane] = Qs[(size_t)n * HH + lane];

    // compact allowed columns (edges + diagonal folded in here)
    unsigned long long w = mask[(size_t)n * MASKW + lane];
    if (lane == (n >> 6)) w |= 1ull << (n & 63);
    int c = __popcll(w);
    int inc = c;
    #pragma unroll
    for (int i = 1; i < 64; i <<= 1) {
        int v = __shfl_up(inc, i, 64);
        if (lane >= i) inc += v;
    }
    int off = inc - c;                 // exclusive prefix
    int deg = __shfl(inc, 63, 64);
    if (deg > CAP) deg = CAP;
    while (w) {
        int b = __builtin_ctzll(w);
        w &= w - 1;
        if (off < CAP) cols_s[wv][off] = lane * 64 + b;
        ++off;
    }

    float mcur[NHEAD], lsum[NHEAD], oacc[NHEAD][HD];
    #pragma unroll
    for (int h = 0; h < NHEAD; ++h) {
        mcur[h] = -INFINITY; lsum[h] = 0.f;
        #pragma unroll
        for (int d = 0; d < HD; ++d) oacc[h][d] = 0.f;
    }

    for (int base = 0; base < deg; base += 64) {
        const int jj = base + lane;
        const bool act = jj < deg;
        const int col = act ? cols_s[wv][jj] : 0;
        float t = temporal[((size_t)n * NN + col) * 2];   // one HBM gather per (row,col)
        const float* kp = Ks + (size_t)col * HH;
        const float* vp = Vs + (size_t)col * HH;
        float tb = sqrtf(t * tbmul);
        #pragma unroll
        for (int h = 0; h < NHEAD; ++h) {
            float s = 0.f;
            #pragma unroll
            for (int d = 0; d < HD; ++d) s += qs_s[wv][h * HD + d] * kp[h * HD + d];
            s = s * scale - tb;
            if (act) {
                if (s > mcur[h]) {
                    float f = __expf(mcur[h] - s);
                    lsum[h] *= f;
                    #pragma unroll
                    for (int d = 0; d < HD; ++d) oacc[h][d] *= f;
                    mcur[h] = s;
                }
                float p = __expf(s - mcur[h]);
                lsum[h] += p;
                #pragma unroll
                for (int d = 0; d < HD; ++d) oacc[h][d] += p * vp[h * HD + d];
            }
        }
    }

    // merge + fused out-projection, wave-local (wsum64 broadcasts to all lanes)
    float accum = (lane < HH) ? bo[lane] : 0.f;
    #pragma unroll
    for (int h = 0; h < NHEAD; ++h) {
        float M = wmax64(mcur[h]);
        float sc = (mcur[h] == -INFINITY) ? 0.f : __expf(mcur[h] - M);
        float L = wsum64(lsum[h] * sc);
        float inv = 1.f / L;
        float part = 0.f;
        #pragma unroll
        for (int d = 0; d < HD; ++d) {
            float o = wsum64(oacc[h][d] * sc);
            float wcol = (lane < HH) ? Wo[(h * HD + d) * HH + lane] : 0.f;
            part += o * wcol;
        }
        accum += part * inv;
    }
    if (lane < HH) out[(size_t)n * HH + lane] = accum;
}

extern "C" void kernel_launch(void* const* d_in, const int* in_sizes, int n_in,
                              void* d_out, int out_size, void* d_ws, size_t ws_size,
                              hipStream_t stream) {
    const float* nf       = (const float*)d_in[0];
    const int*   ei       = (const int*)d_in[1];
    const float* temporal = (const float*)d_in[2];
    const float* Wp = (const float*)d_in[3];
    const float* bp = (const float*)d_in[4];
    const float* Wq = (const float*)d_in[5];
    const float* bq = (const float*)d_in[6];
    const float* Wk = (const float*)d_in[7];
    const float* bk = (const float*)d_in[8];
    const float* Wv = (const float*)d_in[9];
    const float* bv = (const float*)d_in[10];
    const float* Wo = (const float*)d_in[11];
    const float* bo = (const float*)d_in[12];
    float* outp = (float*)d_out;

    char* ws = (char*)d_ws;
    unsigned long long* mask = (unsigned long long*)ws;        // 2 MB
    float* Qs = (float*)(ws + (2u << 20));
    float* Ks = Qs + NN * HH;
    float* Vs = Ks + NN * HH;

    proj_zero<<<NN / NPB, 256, 0, stream>>>(nf, Wp, bp, Wq, bq, Wk, bk, Wv, bv,
                                            mask, Qs, Ks, Vs);
    build_mask<<<(NEDGE + 255) / 256, 256, 0, stream>>>(ei, mask);
    attn_fused<<<NN / 4, 256, 0, stream>>>(Qs, Ks, Vs, temporal, mask, Wo, bo, outp);
}

// Round 8
// 44.407 us; speedup vs baseline: 1.3818x; 1.3818x over previous
//
#include <hip/hip_runtime.h>
#include <math.h>

#define NN 4096
#define INDIM 45
#define HH 44
#define NHEAD 4
#define HD 11
#define NEDGE 131072
#define CAP 128            // max allowed cols per row (deg ~ Poisson(32)+diag; max ~70)
#define MASKW (NN / 64)
#define NPB 8              // nodes per block in proj_zero

__device__ __forceinline__ float wsum64(float v) {
    #pragma unroll
    for (int i = 32; i > 0; i >>= 1) v += __shfl_xor(v, i, 64);
    return v;
}
__device__ __forceinline__ float wmax64(float v) {
    #pragma unroll
    for (int i = 32; i > 0; i >>= 1) v = fmaxf(v, __shfl_xor(v, i, 64));
    return v;
}

// ---------------- Kernel 1: zero mask + fused input/QKV projection ----------------
// Q layout: [n][h][12] (pad 1), KV layout: [n][h][24] (K at +0..10, V at +12..22) —
// 96B stride, 16B-aligned K and V bases -> 6 float4 loads, 2 cache lines per (col,h).
__global__ __launch_bounds__(256)
void proj_zero(const float* __restrict__ nf,
               const float* __restrict__ Wp, const float* __restrict__ bp,
               const float* __restrict__ Wq, const float* __restrict__ bq,
               const float* __restrict__ Wk, const float* __restrict__ bk,
               const float* __restrict__ Wv, const float* __restrict__ bv,
               unsigned long long* __restrict__ mask,
               float* __restrict__ Qp, float* __restrict__ KVp) {
    const int tid = threadIdx.x;
    const int gsz = gridDim.x * 256;
    for (int i = blockIdx.x * 256 + tid; i < NN * MASKW; i += gsz) mask[i] = 0ull;

    __shared__ float xs[NPB][HH];
    const int n0 = blockIdx.x * NPB;
    for (int idx = tid; idx < NPB * HH; idx += 256) {
        int nl = idx / HH, j = idx - nl * HH;
        const float* row = nf + (size_t)(n0 + nl) * INDIM;
        float a = bp[j];
        #pragma unroll
        for (int k = 0; k < INDIM; ++k) a += row[k] * Wp[k * HH + j];
        xs[nl][j] = a;
    }
    __syncthreads();
    for (int idx = tid; idx < NPB * HH; idx += 256) {
        int nl = idx / HH, j = idx - nl * HH;
        const float* row = xs[nl];
        float aq = bq[j], ak = bk[j], av = bv[j];
        #pragma unroll
        for (int k = 0; k < HH; ++k) {
            float xv = row[k];
            aq += xv * Wq[k * HH + j];
            ak += xv * Wk[k * HH + j];
            av += xv * Wv[k * HH + j];
        }
        int h = j / HD, d = j - h * HD;
        size_t nh = (size_t)(n0 + nl) * NHEAD + h;
        Qp[nh * 12 + d]       = aq;
        KVp[nh * 24 + d]      = ak;
        KVp[nh * 24 + 12 + d] = av;
    }
}

// ---------------- Kernel 2: scatter edges (diagonal folded into attn) ----------------
__global__ __launch_bounds__(256)
void build_mask(const int* __restrict__ ei, unsigned long long* __restrict__ mask) {
    int i = blockIdx.x * blockDim.x + threadIdx.x;
    if (i < NEDGE) {
        int r = ei[i];          // query
        int c = ei[NEDGE + i];  // key
        atomicOr(&mask[(size_t)r * MASKW + (c >> 6)], 1ull << (c & 63));
    }
}

// ---------------- Kernel 3: sparse attention + fused output projection ----------------
// Block = one query row, wave h = head h. Wave 0 compacts the mask row AND gathers
// the shared temporal bias into LDS (before the one existing sync), so the 134MB-array
// gather happens once per row instead of once per (row,head). deg<=64 fast path does
// direct (non-online) softmax: 13 butterfly reductions, no rescale branches.
__global__ __launch_bounds__(256)
void attn_out(const float* __restrict__ Qp, const float* __restrict__ KVp,
              const float* __restrict__ temporal,
              const unsigned long long* __restrict__ mask,
              const float* __restrict__ Wo, const float* __restrict__ bo,
              float* __restrict__ out) {
    const int tid = threadIdx.x;
    const int lane = tid & 63;
    const int h = tid >> 6;
    const int n = blockIdx.x;
    const float scale = 0.30151134457776363f;  // 1/sqrt(11)
    const float tbmul = 9.99990000099999f;     // 1/(0.1+1e-6)

    __shared__ int cols_s[CAP];
    __shared__ float tb_s[CAP];
    __shared__ int deg_s;
    __shared__ float att_s[HH];

    if (h == 0) {   // wave 0: compact allowed cols (edges + diag), gather temporal bias
        unsigned long long w = mask[(size_t)n * MASKW + lane];
        if (lane == (n >> 6)) w |= 1ull << (n & 63);
        int c = __popcll(w);
        int inc = c;
        #pragma unroll
        for (int i = 1; i < 64; i <<= 1) {
            int v = __shfl_up(inc, i, 64);
            if (lane >= i) inc += v;
        }
        int off = inc - c;                 // exclusive prefix
        int deg = __shfl(inc, 63, 64);
        if (deg > CAP) deg = CAP;
        while (w) {
            int b = __builtin_ctzll(w);
            w &= w - 1;
            if (off < CAP) cols_s[off] = lane * 64 + b;
            ++off;
        }
        if (lane == 0) deg_s = deg;
        for (int j = lane; j < deg; j += 64) {     // intra-wave: cols_s visible in order
            int col = cols_s[j];
            tb_s[j] = sqrtf(temporal[((size_t)n * NN + col) * 2] * tbmul);
        }
    }
    __syncthreads();
    const int deg = deg_s;

    const float4* qp4 = (const float4*)(Qp + ((size_t)n * NHEAD + h) * 12);
    float4 q0 = qp4[0], q1 = qp4[1], q2 = qp4[2];

    if (deg <= 64) {
        // ---- fast path: single chunk, direct softmax ----
        const bool act = lane < deg;
        const int col = act ? cols_s[lane] : 0;
        const float4* kv4 = (const float4*)(KVp + ((size_t)col * NHEAD + h) * 24);
        float4 a0 = kv4[0], a1 = kv4[1], a2 = kv4[2];
        float4 b0 = kv4[3], b1 = kv4[4], b2 = kv4[5];
        float s = q0.x*a0.x + q0.y*a0.y + q0.z*a0.z + q0.w*a0.w
                + q1.x*a1.x + q1.y*a1.y + q1.z*a1.z + q1.w*a1.w
                + q2.x*a2.x + q2.y*a2.y + q2.z*a2.z;
        s = act ? s * scale - tb_s[lane] : -INFINITY;
        float M = wmax64(s);
        float p = act ? __expf(s - M) : 0.f;
        float L = wsum64(p);
        float inv = 1.f / L;
        float vv[12] = {b0.x,b0.y,b0.z,b0.w, b1.x,b1.y,b1.z,b1.w, b2.x,b2.y,b2.z,b2.w};
        #pragma unroll
        for (int d = 0; d < HD; ++d) {
            float o = wsum64(p * vv[d]);
            if (lane == d) att_s[h * HD + d] = o * inv;
        }
    } else {
        // ---- fallback: online softmax over 64-col chunks ----
        float mcur = -INFINITY, lsum = 0.f, oacc[HD];
        #pragma unroll
        for (int d = 0; d < HD; ++d) oacc[d] = 0.f;
        for (int base = 0; base < deg; base += 64) {
            const int jj = base + lane;
            const bool act = jj < deg;
            const int col = act ? cols_s[jj] : 0;
            const float4* kv4 = (const float4*)(KVp + ((size_t)col * NHEAD + h) * 24);
            float4 a0 = kv4[0], a1 = kv4[1], a2 = kv4[2];
            float4 b0 = kv4[3], b1 = kv4[4], b2 = kv4[5];
            float s = q0.x*a0.x + q0.y*a0.y + q0.z*a0.z + q0.w*a0.w
                    + q1.x*a1.x + q1.y*a1.y + q1.z*a1.z + q1.w*a1.w
                    + q2.x*a2.x + q2.y*a2.y + q2.z*a2.z;
            float vv[12] = {b0.x,b0.y,b0.z,b0.w, b1.x,b1.y,b1.z,b1.w, b2.x,b2.y,b2.z,b2.w};
            if (act) {
                s = s * scale - tb_s[jj];
                if (s > mcur) {
                    float f = __expf(mcur - s);
                    lsum *= f;
                    #pragma unroll
                    for (int d = 0; d < HD; ++d) oacc[d] *= f;
                    mcur = s;
                }
                float p = __expf(s - mcur);
                lsum += p;
                #pragma unroll
                for (int d = 0; d < HD; ++d) oacc[d] += p * vv[d];
            }
        }
        float M = wmax64(mcur);
        float sc = (mcur == -INFINITY) ? 0.f : __expf(mcur - M);
        float L = wsum64(lsum * sc);
        float inv = 1.f / L;
        #pragma unroll
        for (int d = 0; d < HD; ++d) {
            float o = wsum64(oacc[d] * sc);
            if (lane == d) att_s[h * HD + d] = o * inv;
        }
    }
    __syncthreads();

    if (tid < HH) {
        float a = bo[tid];
        #pragma unroll
        for (int k = 0; k < HH; ++k) a += att_s[k] * Wo[k * HH + tid];
        out[(size_t)n * HH + tid] = a;
    }
}

extern "C" void kernel_launch(void* const* d_in, const int* in_sizes, int n_in,
                              void* d_out, int out_size, void* d_ws, size_t ws_size,
                              hipStream_t stream) {
    const float* nf       = (const float*)d_in[0];
    const int*   ei       = (const int*)d_in[1];
    const float* temporal = (const float*)d_in[2];
    const float* Wp = (const float*)d_in[3];
    const float* bp = (const float*)d_in[4];
    const float* Wq = (const float*)d_in[5];
    const float* bq = (const float*)d_in[6];
    const float* Wk = (const float*)d_in[7];
    const float* bk = (const float*)d_in[8];
    const float* Wv = (const float*)d_in[9];
    const float* bv = (const float*)d_in[10];
    const float* Wo = (const float*)d_in[11];
    const float* bo = (const float*)d_in[12];
    float* outp = (float*)d_out;

    char* ws = (char*)d_ws;
    unsigned long long* mask = (unsigned long long*)ws;        // 2 MB
    float* Qp  = (float*)(ws + (2u << 20));                    // NN*4*12 floats
    float* KVp = Qp + (size_t)NN * NHEAD * 12;                 // NN*4*24 floats

    proj_zero<<<NN / NPB, 256, 0, stream>>>(nf, Wp, bp, Wq, bq, Wk, bk, Wv, bv,
                                            mask, Qp, KVp);
    build_mask<<<(NEDGE + 255) / 256, 256, 0, stream>>>(ei, mask);
    attn_out<<<NN, 256, 0, stream>>>(Qp, KVp, temporal, mask, Wo, bo, outp);
}